// Round 13
// baseline (58.166 us; speedup 1.0000x reference)
//
#include <hip/hip_runtime.h>
#include <hip/hip_bf16.h>

typedef __bf16 bf16x8 __attribute__((ext_vector_type(8)));
typedef float  f32x4  __attribute__((ext_vector_type(4)));

#define NTILES 16384               // 262144 rows / 16

// ---------------------------------------------------------------------------
// Kernel 1 (one-shot): expand quaternion weight (32,32,4) -> W_eff (128x128)
// bf16, MFMA A-fragment order, k-axis PERMUTED for full-granule direct loads
// (verbatim r4/r5/r10, HW-verified):
//   element j of fragment (nt,kb,lane) holds physical
//     k = kb*32 + (j<4 ? g*4+j : 16 + g*4 + (j-4)),  g = lane>>4
// ---------------------------------------------------------------------------
__global__ __launch_bounds__(256) void prep_wfrag(const float* __restrict__ w,
                                                  ushort* __restrict__ wfrag) {
    int t = blockIdx.x * 256 + threadIdx.x;
    if (t >= 128 * 128) return;
    int j    = t & 7;
    int lane = (t >> 3) & 63;
    int kb   = (t >> 9) & 3;
    int nt   = t >> 11;
    int g    = lane >> 4;
    int n = nt * 16 + (lane & 15);
    int k = kb * 32 + (j < 4 ? g * 4 + j : 16 + g * 4 + (j - 4));
    int o  = n >> 2, c = n & 3;
    int nq = k >> 2, d = k & 3;
    int comp = c ^ d;                   // Hamilton tables (verified r1-r12)
    bool neg = (d != 0) && ((c == 0) || (c != d && d != (c % 3) + 1));
    float val = w[o * 128 + nq * 4 + comp];
    val = neg ? -val : val;
    __bf16 bv = (__bf16)val;
    wfrag[t] = *reinterpret_cast<ushort*>(&bv);
}

// ---------------------------------------------------------------------------
// Kernel 2: out = x @ W_eff^T + bias.  ZERO barriers: W fragments and bias
// are read per-wave straight from global (L2-resident 32KB), LDS is purely a
// per-wave-private 8KB store stage.  Waves are fully independent ->
// dispatch-staggered phases -> continuous interleaved read/write issue
// (the copy-bench pattern).  Store path = r10's staged full-line nt scheme.
// ---------------------------------------------------------------------------
__global__ __launch_bounds__(256, 4) void qgemm(const float* __restrict__ x,
                                                const ushort* __restrict__ wfrag,
                                                const float* __restrict__ bias,
                                                float* __restrict__ out) {
    __shared__ __align__(16) float stage[4][2048];   // 8 KB per wave, private

    int tid   = threadIdx.x;
    int lane  = tid & 63;
    int wid   = tid >> 6;      // 0..3
    int row16 = lane & 15;
    int kgrp  = lane >> 4;     // 0..3
    int loff  = row16 * 128 + kgrp * 4;

    // 1) x loads (8 x dwordx4, full-granule coalesced via k-permutation)
    size_t tile = (size_t)blockIdx.x * 4 + wid;      // 0..16383
    const float4* xv = (const float4*)(x + tile * 2048 + loff);
    float4 r[8];
#pragma unroll
    for (int kb = 0; kb < 4; ++kb) {
        r[2 * kb]     = xv[kb * 8];
        r[2 * kb + 1] = xv[kb * 8 + 4];
    }

    // 2) cvt x -> bf16 fragments
    bf16x8 afr[4];
#pragma unroll
    for (int kb = 0; kb < 4; ++kb) {
        float4 p = r[2 * kb], q = r[2 * kb + 1];
        afr[kb][0] = (__bf16)p.x; afr[kb][1] = (__bf16)p.y;
        afr[kb][2] = (__bf16)p.z; afr[kb][3] = (__bf16)p.w;
        afr[kb][4] = (__bf16)q.x; afr[kb][5] = (__bf16)q.y;
        afr[kb][6] = (__bf16)q.z; afr[kb][7] = (__bf16)q.w;
    }

    // 3) MFMA, W fragments streamed from global (L2-hot; compiler pipelines
    //    the loads into the MFMA chain).  acc[nt] = features nt*16+kgrp*4..+3
    //    of batch row row16, bias preloaded into the accumulator.
    const bf16x8* wg = (const bf16x8*)wfrag;
    f32x4 acc[8];
#pragma unroll
    for (int nt = 0; nt < 8; ++nt) {
        acc[nt] = *(const f32x4*)(bias + nt * 16 + kgrp * 4);   // L2-hot
#pragma unroll
        for (int kb = 0; kb < 4; ++kb) {
            bf16x8 wfr = wg[(nt * 4 + kb) * 64 + lane];          // L2-hot
            acc[nt] = __builtin_amdgcn_mfma_f32_16x16x32_bf16(wfr, afr[kb], acc[nt], 0, 0, 0);
        }
    }

    // 4) stage acc into this wave's private 8KB slice, XOR-swizzled (r10):
    //    logical chunk c = nt*4+kgrp (features 4c..4c+3) of row row16 lives
    //    at physical chunk c ^ (row16&7).
    float* stg = stage[wid];
#pragma unroll
    for (int nt = 0; nt < 8; ++nt) {
        int c = nt * 4 + kgrp;
        *(f32x4*)(stg + row16 * 128 + ((c ^ (row16 & 7)) << 2)) = acc[nt];
    }
    asm volatile("s_waitcnt lgkmcnt(0)" ::: "memory");
    __builtin_amdgcn_sched_barrier(0);

    // 5) 8 x 1KB-contiguous non-temporal stores (full 128B lines/instruction)
    f32x4* ob = (f32x4*)(out + tile * 2048);
#pragma unroll
    for (int s = 0; s < 8; ++s) {
        int p   = lane + 64 * s;      // 16B-chunk index 0..511
        int row = p >> 5;             // 0..15
        int c   = p & 31;
        f32x4 v = *(const f32x4*)(stg + row * 128 + ((c ^ (row & 7)) << 2));
        __builtin_nontemporal_store(v, ob + p);
    }
}

extern "C" void kernel_launch(void* const* d_in, const int* in_sizes, int n_in,
                              void* d_out, int out_size, void* d_ws, size_t ws_size,
                              hipStream_t stream) {
    const float* x      = (const float*)d_in[0];   // [262144,128] fp32
    const float* weight = (const float*)d_in[1];   // [32,32,4] fp32
    const float* bias   = (const float*)d_in[2];   // [128] fp32
    float*       out    = (float*)d_out;           // [262144,128] fp32
    ushort*      wfrag  = (ushort*)d_ws;           // 32 KB fragment-ordered W_eff

    prep_wfrag<<<64, 256, 0, stream>>>(weight, wfrag);
    qgemm<<<4096, 256, 0, stream>>>(x, wfrag, bias, out);
}

// Round 14
// 50.879 us; speedup vs baseline: 1.1432x; 1.1432x over previous
//
#include <hip/hip_runtime.h>
#include <hip/hip_bf16.h>

typedef __bf16 bf16x8 __attribute__((ext_vector_type(8)));
typedef float  f32x4  __attribute__((ext_vector_type(4)));

#define NT_PER_WAVE 16
#define GEMM_BLOCKS 256            // 1 block/CU, 4 waves x 16 tiles = 16384 tiles

// ---------------------------------------------------------------------------
// Kernel 1 (one-shot): expand quaternion weight (32,32,4) -> W_eff (128x128)
// bf16, MFMA A-fragment order, k-axis PERMUTED (verbatim r4-r12, HW-verified):
//   element j of fragment (nt,kb,lane) holds physical
//     k = kb*32 + (j<4 ? g*4+j : 16 + g*4 + (j-4)),  g = lane>>4
// ---------------------------------------------------------------------------
__global__ __launch_bounds__(256) void prep_wfrag(const float* __restrict__ w,
                                                  ushort* __restrict__ wfrag) {
    int t = blockIdx.x * 256 + threadIdx.x;
    if (t >= 128 * 128) return;
    int j    = t & 7;
    int lane = (t >> 3) & 63;
    int kb   = (t >> 9) & 3;
    int nt   = t >> 11;
    int g    = lane >> 4;
    int n = nt * 16 + (lane & 15);
    int k = kb * 32 + (j < 4 ? g * 4 + j : 16 + g * 4 + (j - 4));
    int o  = n >> 2, c = n & 3;
    int nq = k >> 2, d = k & 3;
    int comp = c ^ d;                   // Hamilton tables (verified r1-r13)
    bool neg = (d != 0) && ((c == 0) || (c != d && d != (c % 3) + 1));
    float val = w[o * 128 + nq * 4 + comp];
    val = neg ? -val : val;
    __bf16 bv = (__bf16)val;
    wfrag[t] = *reinterpret_cast<ushort*>(&bv);
}

// ---------------------------------------------------------------------------
// Kernel 2: out = x @ W_eff^T + bias.  Barrier-free deep pipeline:
//  - W in 128 VGPRs/wave (one coalesced L2 read), LDS = per-wave 2x8KB x-ring
//  - x staged via global_load_lds (no VGPR cost) with ROTATED source so the
//    linear DMA lands a bank-uniform layout: slot(r,c) = r*32 + ((c+2r)&31)
//    16B-chunks; fragment reads are then uniform 2-way (free)
//  - counted s_waitcnt vmcnt(16/8): one tile of loads + one tile of stores
//    stay in HBM flight per wave at all times
//  - store path = r10's staged full-line non-temporal scheme, reusing the
//    just-consumed ring buffer
// ---------------------------------------------------------------------------
__global__ __launch_bounds__(256, 1) void qgemm(const float* __restrict__ x,
                                                const ushort* __restrict__ wfrag,
                                                const float* __restrict__ bias,
                                                float* __restrict__ out) {
    __shared__ __align__(16) float xring[4][2][2048];   // 64 KB: 4 waves x 2 x 8KB

    int tid   = threadIdx.x;
    int lane  = tid & 63;
    int wid   = tid >> 6;      // 0..3
    int row16 = lane & 15;
    int kgrp  = lane >> 4;     // 0..3

    // --- W fragments -> 128 VGPRs (32 x dwordx4, each instr = 1KB contiguous, L2-hot)
    const bf16x8* wg = (const bf16x8*)wfrag;
    bf16x8 wreg[32];
#pragma unroll
    for (int f = 0; f < 32; ++f) wreg[f] = wg[f * 64 + lane];

    // --- bias -> 32 VGPRs (L2-hot)
    f32x4 bv[8];
#pragma unroll
    for (int nt = 0; nt < 8; ++nt) bv[nt] = *(const f32x4*)(bias + nt * 16 + kgrp * 4);

    size_t tile0 = ((size_t)blockIdx.x * 4 + wid) * NT_PER_WAVE;  // 16 consecutive tiles
    float* buf0 = xring[wid][0];
    float* buf1 = xring[wid][1];

    // stage: tile -> buf via 8 global_load_lds (1KB linear LDS per instr);
    // source chunk pre-rotated: slot s=(64I+l) gets global chunk r*32+((pc-2r)&31)
    auto stage = [&](float* buf, size_t t) {
        const char* tb = (const char*)(x + t * 2048);
#pragma unroll
        for (int I = 0; I < 8; ++I) {
            int s  = I * 64 + lane;
            int rr = s >> 5;
            int pc = s & 31;
            int gc = rr * 32 + ((pc - 2 * rr) & 31);
            __builtin_amdgcn_global_load_lds(
                (const __attribute__((address_space(1))) void*)(tb + gc * 16),
                (__attribute__((address_space(3))) void*)(buf + I * 256),
                16, 0, 0);
        }
    };

    stage(buf0, tile0);
    stage(buf1, tile0 + 1);

#pragma unroll
    for (int i = 0; i < NT_PER_WAVE; ++i) {
        float* cur = (i & 1) ? buf1 : buf0;

        // counted wait: guarantee stage(tile i) complete; newer ops stay in flight
        if (i == 0 || i == NT_PER_WAVE - 1)
            asm volatile("s_waitcnt vmcnt(8)" ::: "memory");
        else
            asm volatile("s_waitcnt vmcnt(16)" ::: "memory");
        __builtin_amdgcn_sched_barrier(0);

        // fragment reads from rotated layout + cvt -> bf16
        bf16x8 afr[4];
#pragma unroll
        for (int kb = 0; kb < 4; ++kb) {
            int c1 = 8 * kb + kgrp;
            int c2 = 8 * kb + 4 + kgrp;
            f32x4 lo = *(const f32x4*)(cur + row16 * 128 + (((c1 + 2 * row16) & 31) << 2));
            f32x4 hi = *(const f32x4*)(cur + row16 * 128 + (((c2 + 2 * row16) & 31) << 2));
            afr[kb][0] = (__bf16)lo[0]; afr[kb][1] = (__bf16)lo[1];
            afr[kb][2] = (__bf16)lo[2]; afr[kb][3] = (__bf16)lo[3];
            afr[kb][4] = (__bf16)hi[0]; afr[kb][5] = (__bf16)hi[1];
            afr[kb][6] = (__bf16)hi[2]; afr[kb][7] = (__bf16)hi[3];
        }

        // MFMA from registers: acc[nt] = features nt*16+kgrp*4..+3 of row row16
        f32x4 acc[8];
#pragma unroll
        for (int nt = 0; nt < 8; ++nt) {
            acc[nt] = bv[nt];
#pragma unroll
            for (int kb = 0; kb < 4; ++kb)
                acc[nt] = __builtin_amdgcn_mfma_f32_16x16x32_bf16(wreg[nt * 4 + kb], afr[kb], acc[nt], 0, 0, 0);
        }

        // staged store (r10 scheme) reusing cur: data-dep (afr->acc) orders the
        // ds_writes after the fragment ds_reads
#pragma unroll
        for (int nt = 0; nt < 8; ++nt) {
            int c = nt * 4 + kgrp;
            *(f32x4*)(cur + row16 * 128 + ((c ^ (row16 & 7)) << 2)) = acc[nt];
        }
        asm volatile("s_waitcnt lgkmcnt(0)" ::: "memory");
        __builtin_amdgcn_sched_barrier(0);

        f32x4* ob = (f32x4*)(out + (tile0 + i) * 2048);
#pragma unroll
        for (int s = 0; s < 8; ++s) {
            int p   = lane + 64 * s;
            int row = p >> 5;
            int c   = p & 31;
            f32x4 v = *(const f32x4*)(cur + row * 128 + ((c ^ (row & 7)) << 2));
            __builtin_nontemporal_store(v, ob + p);
        }
        __builtin_amdgcn_sched_barrier(0);

        // refill cur with tile i+2 (store-phase ds_reads already retired:
        // their results were consumed by the nt stores above)
        if (i + 2 < NT_PER_WAVE) stage(cur, tile0 + i + 2);
        __builtin_amdgcn_sched_barrier(0);
    }
}

extern "C" void kernel_launch(void* const* d_in, const int* in_sizes, int n_in,
                              void* d_out, int out_size, void* d_ws, size_t ws_size,
                              hipStream_t stream) {
    const float* x      = (const float*)d_in[0];   // [262144,128] fp32
    const float* weight = (const float*)d_in[1];   // [32,32,4] fp32
    const float* bias   = (const float*)d_in[2];   // [128] fp32
    float*       out    = (float*)d_out;           // [262144,128] fp32
    ushort*      wfrag  = (ushort*)d_ws;           // 32 KB fragment-ordered W_eff

    prep_wfrag<<<64, 256, 0, stream>>>(weight, wfrag);
    qgemm<<<GEMM_BLOCKS, 256, 0, stream>>>(x, wfrag, bias, out);
}

// Round 15
// 49.225 us; speedup vs baseline: 1.1816x; 1.0336x over previous
//
#include <hip/hip_runtime.h>
#include <hip/hip_bf16.h>

typedef __bf16 bf16x8 __attribute__((ext_vector_type(8)));
typedef float  f32x4  __attribute__((ext_vector_type(4)));

#define NTILES 16384               // 262144 rows / 16

// ---------------------------------------------------------------------------
// Kernel 1 (one-shot): expand quaternion weight (32,32,4) -> W_eff (128x128)
// bf16, MFMA A-fragment order, k-axis PERMUTED for full-granule direct loads
// (HW-verified rounds 4-14):
//   element j of fragment (nt,kb,lane) holds physical
//     k = kb*32 + (j<4 ? g*4+j : 16 + g*4 + (j-4)),  g = lane>>4
// ---------------------------------------------------------------------------
__global__ __launch_bounds__(256) void prep_wfrag(const float* __restrict__ w,
                                                  ushort* __restrict__ wfrag) {
    int t = blockIdx.x * 256 + threadIdx.x;
    if (t >= 128 * 128) return;
    int j    = t & 7;
    int lane = (t >> 3) & 63;
    int kb   = (t >> 9) & 3;
    int nt   = t >> 11;
    int g    = lane >> 4;
    int n = nt * 16 + (lane & 15);
    int k = kb * 32 + (j < 4 ? g * 4 + j : 16 + g * 4 + (j - 4));
    int o  = n >> 2, c = n & 3;
    int nq = k >> 2, d = k & 3;
    int comp = c ^ d;                   // Hamilton tables (verified r1-r14)
    bool neg = (d != 0) && ((c == 0) || (c != d && d != (c % 3) + 1));
    float val = w[o * 128 + nq * 4 + comp];
    val = neg ? -val : val;
    __bf16 bv = (__bf16)val;
    wfrag[t] = *reinterpret_cast<ushort*>(&bv);
}

// ---------------------------------------------------------------------------
// Kernel 2 (r10, best measured: 49.2 us): out = x @ W_eff^T + bias.
// Flat 1 tile/wave.  Input: k-permuted direct register loads (granule-clean).
// Output: after block barrier, wlds (W dead) reused as 4 x 8KB per-wave
// staging; full-wave swizzled acc writes, explicit lgkmcnt(0) fence, then
// 8 x 1KB-contiguous non-temporal stores (full 128B lines per instruction).
// ---------------------------------------------------------------------------
__global__ __launch_bounds__(256, 4) void qgemm(const float* __restrict__ x,
                                                const ushort* __restrict__ wfrag,
                                                const float* __restrict__ bias,
                                                float* __restrict__ out) {
    __shared__ __align__(16) ushort wlds[16384];   // 32 KB: W fragments, later store stage
    __shared__ __align__(16) float  sbias[128];

    int tid   = threadIdx.x;
    int lane  = tid & 63;
    int wid   = tid >> 6;      // 0..3
    int row16 = lane & 15;
    int kgrp  = lane >> 4;     // 0..3
    int loff  = row16 * 128 + kgrp * 4;

    // 1) W-copy loads first (x loads stay in flight through the ds_write wait)
    int4 wtmp[8];
    {
        const int4* src = (const int4*)wfrag;
#pragma unroll
        for (int i = 0; i < 8; ++i) wtmp[i] = src[tid + i * 256];
    }

    // 2) x loads (8 x dwordx4, full-granule coalesced via k-permutation)
    size_t tile = (size_t)blockIdx.x * 4 + wid;    // 0..16383
    const float4* xv = (const float4*)(x + tile * 2048 + loff);
    float4 r[8];
#pragma unroll
    for (int kb = 0; kb < 4; ++kb) {
        r[2 * kb]     = xv[kb * 8];
        r[2 * kb + 1] = xv[kb * 8 + 4];
    }

    // 3) W -> LDS, bias -> LDS, barrier
    {
        int4* dst = (int4*)wlds;
#pragma unroll
        for (int i = 0; i < 8; ++i) dst[tid + i * 256] = wtmp[i];
    }
    if (tid < 128) sbias[tid] = bias[tid];
    __syncthreads();

    // 4) cvt x -> bf16 fragments
    bf16x8 afr[4];
#pragma unroll
    for (int kb = 0; kb < 4; ++kb) {
        float4 p = r[2 * kb], q = r[2 * kb + 1];
        afr[kb][0] = (__bf16)p.x; afr[kb][1] = (__bf16)p.y;
        afr[kb][2] = (__bf16)p.z; afr[kb][3] = (__bf16)p.w;
        afr[kb][4] = (__bf16)q.x; afr[kb][5] = (__bf16)q.y;
        afr[kb][6] = (__bf16)q.z; afr[kb][7] = (__bf16)q.w;
    }

    // 5) MFMA: acc[nt] = features nt*16+kgrp*4..+3 of batch row row16 (+bias)
    const bf16x8* blds = (const bf16x8*)wlds;
    f32x4 acc[8];
#pragma unroll
    for (int nt = 0; nt < 8; ++nt) {
        acc[nt] = *(const f32x4*)&sbias[nt * 16 + kgrp * 4];
#pragma unroll
        for (int kb = 0; kb < 4; ++kb) {
            bf16x8 wfr = blds[(nt * 4 + kb) * 64 + lane];
            acc[nt] = __builtin_amdgcn_mfma_f32_16x16x32_bf16(wfr, afr[kb], acc[nt], 0, 0, 0);
        }
    }

    // 6) all waves done reading W -> wlds reusable as store stage
    __syncthreads();

    // 7) stage acc into my wave's 8KB slice, XOR-swizzled:
    //    logical chunk c (= nt*4+kgrp, features 4c..4c+3) of row row16 lives at
    //    physical chunk c ^ (row16&7).  Full-wave, no divergence.
    float* stg = (float*)wlds + wid * 2048;
#pragma unroll
    for (int nt = 0; nt < 8; ++nt) {
        int c = nt * 4 + kgrp;
        *(f32x4*)(stg + row16 * 128 + ((c ^ (row16 & 7)) << 2)) = acc[nt];
    }
    asm volatile("s_waitcnt lgkmcnt(0)" ::: "memory");
    __builtin_amdgcn_sched_barrier(0);

    // 8) 8 x 1KB-contiguous non-temporal stores (full 128B lines/instruction)
    f32x4* ob = (f32x4*)(out + tile * 2048);
#pragma unroll
    for (int s = 0; s < 8; ++s) {
        int p   = lane + 64 * s;      // 16B-chunk index 0..511
        int row = p >> 5;             // 0..15
        int c   = p & 31;
        f32x4 v = *(const f32x4*)(stg + row * 128 + ((c ^ (row & 7)) << 2));
        __builtin_nontemporal_store(v, ob + p);
    }
}

extern "C" void kernel_launch(void* const* d_in, const int* in_sizes, int n_in,
                              void* d_out, int out_size, void* d_ws, size_t ws_size,
                              hipStream_t stream) {
    const float* x      = (const float*)d_in[0];   // [262144,128] fp32
    const float* weight = (const float*)d_in[1];   // [32,32,4] fp32
    const float* bias   = (const float*)d_in[2];   // [128] fp32
    float*       out    = (float*)d_out;           // [262144,128] fp32
    ushort*      wfrag  = (ushort*)d_ws;           // 32 KB fragment-ordered W_eff

    prep_wfrag<<<64, 256, 0, stream>>>(weight, wfrag);
    qgemm<<<4096, 256, 0, stream>>>(x, wfrag, bias, out);
}